// Round 3
// baseline (1123.240 us; speedup 1.0000x reference)
//
#include <hip/hip_runtime.h>

// ---------------------------------------------------------------------------
// FlexibleGraphSAGE: 3-layer SAGEConv (mean aggregation), fp32.
//   per layer: out = mean_agg(h) @ Wl^T + bl + h @ Wr^T   (+ReLU on layers 0,1)
// R2 changes vs R1:
//   - GEMM rewritten: row-major LDS tiles (no transposed scatter stores ->
//     no 8-way store conflicts), k-vectorized 4x8 microtile, BN=128 full
//     output width (gy=1, X read once), B-columns interleaved by 16 so
//     fragment reads are 2-way-alias only. Templated BN=64 for layer 2.
// ---------------------------------------------------------------------------

#define D_H 128
#define NB_SCAN 256   // scan blocks; 256*256 = 65536 >= N

__global__ void count_deg_kernel(const int* __restrict__ dst, int* __restrict__ deg, int E) {
    int e = blockIdx.x * blockDim.x + threadIdx.x;
    if (e < E) atomicAdd(&deg[dst[e]], 1);
}

__global__ __launch_bounds__(256) void scan_reduce_kernel(const int* __restrict__ deg,
                                                          int* __restrict__ bsum, int n) {
    __shared__ int s[256];
    int t = threadIdx.x;
    int i = blockIdx.x * 256 + t;
    int v = (i < n) ? deg[i] : 0;
    s[t] = v;
    __syncthreads();
    for (int off = 128; off > 0; off >>= 1) {
        if (t < off) s[t] += s[t + off];
        __syncthreads();
    }
    if (t == 0) bsum[blockIdx.x] = s[0];
}

__global__ __launch_bounds__(256) void scan_offsets_kernel(const int* __restrict__ bsum,
                                                           int* __restrict__ boff,
                                                           int* __restrict__ row_ptr, int n) {
    __shared__ int s[256];
    int t = threadIdx.x;
    int v = bsum[t];
    s[t] = v;
    __syncthreads();
    for (int off = 1; off < 256; off <<= 1) {
        int tmp = (t >= off) ? s[t - off] : 0;
        __syncthreads();
        s[t] += tmp;
        __syncthreads();
    }
    boff[t] = s[t] - v;
    if (t == 255) row_ptr[n] = s[255];
}

__global__ __launch_bounds__(256) void scan_write_kernel(const int* __restrict__ deg,
                                                         const int* __restrict__ boff,
                                                         int* __restrict__ row_ptr,
                                                         int* __restrict__ cursor,
                                                         float* __restrict__ inv_deg, int n) {
    __shared__ int s[256];
    int t = threadIdx.x;
    int i = blockIdx.x * 256 + t;
    int v = (i < n) ? deg[i] : 0;
    s[t] = v;
    __syncthreads();
    for (int off = 1; off < 256; off <<= 1) {
        int tmp = (t >= off) ? s[t - off] : 0;
        __syncthreads();
        s[t] += tmp;
        __syncthreads();
    }
    if (i < n) {
        int excl = s[t] - v + boff[blockIdx.x];
        row_ptr[i] = excl;
        cursor[i] = excl;
        inv_deg[i] = 1.0f / (float)max(v, 1);
    }
}

__global__ void fill_csr_kernel(const int* __restrict__ src, const int* __restrict__ dst,
                                int* __restrict__ cursor, int* __restrict__ col, int E) {
    int e = blockIdx.x * blockDim.x + threadIdx.x;
    if (e < E) {
        int pos = atomicAdd(&cursor[dst[e]], 1);
        col[pos] = src[e];
    }
}

// agg[v] = inv_deg[v] * sum_{u in N(v)} h[u]   (h is [n, 128] fp32)
__global__ __launch_bounds__(256) void aggregate_kernel(const float* __restrict__ h,
                                                        const int* __restrict__ row_ptr,
                                                        const int* __restrict__ col,
                                                        const float* __restrict__ inv_deg,
                                                        float* __restrict__ agg, int n) {
    int wave = threadIdx.x >> 6;
    int lane = threadIdx.x & 63;
    int node = blockIdx.x * 4 + wave;
    if (node >= n) return;
    int beg = row_ptr[node];
    int end = row_ptr[node + 1];
    const int coloff = lane << 1;
    float2 acc = make_float2(0.f, 0.f);
    for (int base = beg; base < end; base += 64) {
        int m = end - base;
        if (m > 64) m = 64;
        int myc = (lane < m) ? col[base + lane] : 0;
        int j = 0;
        for (; j + 4 <= m; j += 4) {
            int u0 = __shfl(myc, j + 0);
            int u1 = __shfl(myc, j + 1);
            int u2 = __shfl(myc, j + 2);
            int u3 = __shfl(myc, j + 3);
            float2 v0 = *(const float2*)&h[(size_t)u0 * D_H + coloff];
            float2 v1 = *(const float2*)&h[(size_t)u1 * D_H + coloff];
            float2 v2 = *(const float2*)&h[(size_t)u2 * D_H + coloff];
            float2 v3 = *(const float2*)&h[(size_t)u3 * D_H + coloff];
            acc.x += v0.x + v1.x + v2.x + v3.x;
            acc.y += v0.y + v1.y + v2.y + v3.y;
        }
        for (; j < m; ++j) {
            int u = __shfl(myc, j);
            float2 v = *(const float2*)&h[(size_t)u * D_H + coloff];
            acc.x += v.x;
            acc.y += v.y;
        }
    }
    float s = inv_deg[node];
    float2 o = make_float2(acc.x * s, acc.y * s);
    *(float2*)&agg[(size_t)node * D_H + coloff] = o;
}

// out[n,c] = relu?( sum_k Xa[n,k]*Wa[c,k] + Xh[n,k]*Wh[c,k] + bias[c] ), K1=128 each half.
// BM=64 rows/block, BN_T = full output width (gy=1). 256 threads = 16(ty) x 16(tx).
// Thread computes 4 rows (m0=ty*4, blocked) x NREG cols (c = tx + 16*j, interleaved).
// Row-major LDS tiles [row][K+4]; all staging/fragment traffic is float4.
template<int BN_T>
__global__ __launch_bounds__(256) void gemm_sage_kernel(
        const float* __restrict__ Xa, const float* __restrict__ Xh,
        const float* __restrict__ Wa, const float* __restrict__ Wh,
        const float* __restrict__ bias, float* __restrict__ out,
        int N, int do_relu) {
    constexpr int KC = 64;
    constexpr int NREG = BN_T / 16;      // 8 (layers 0/1) or 4 (layer 2)
    __shared__ float Xs[64][KC + 4];
    __shared__ float Ws[BN_T][KC + 4];
    const int tid = threadIdx.x;
    const int tx = tid & 15, ty = tid >> 4;
    const int m0 = ty << 2;
    const int row0 = blockIdx.x * 64;
    float acc[4][NREG] = {};

    for (int half = 0; half < 2; ++half) {
        const float* __restrict__ X = half ? Xh : Xa;
        const float* __restrict__ W = half ? Wh : Wa;
        #pragma unroll
        for (int kc = 0; kc < 128; kc += KC) {
            __syncthreads();
            // stage X tile: 64 rows x 16 float4 (contiguous per 16 lanes)
            #pragma unroll
            for (int q = tid; q < 64 * (KC / 4); q += 256) {
                int r = q >> 4, c4 = (q & 15) << 2;
                int row = row0 + r;
                float4 v = make_float4(0.f, 0.f, 0.f, 0.f);
                if (row < N) v = *(const float4*)&X[(size_t)row * 128 + kc + c4];
                *(float4*)&Xs[r][c4] = v;
            }
            // stage W tile: BN_T rows x 16 float4
            #pragma unroll
            for (int q = tid; q < BN_T * (KC / 4); q += 256) {
                int r = q >> 4, c4 = (q & 15) << 2;
                float4 v = *(const float4*)&W[(size_t)r * 128 + kc + c4];
                *(float4*)&Ws[r][c4] = v;
            }
            __syncthreads();
            #pragma unroll
            for (int k4 = 0; k4 < KC; k4 += 4) {
                float4 a[4], b[NREG];
                #pragma unroll
                for (int i = 0; i < 4; ++i) a[i] = *(const float4*)&Xs[m0 + i][k4];
                #pragma unroll
                for (int j = 0; j < NREG; ++j) b[j] = *(const float4*)&Ws[tx + 16 * j][k4];
                #pragma unroll
                for (int i = 0; i < 4; ++i) {
                    #pragma unroll
                    for (int j = 0; j < NREG; ++j) {
                        acc[i][j] += a[i].x * b[j].x;
                        acc[i][j] += a[i].y * b[j].y;
                        acc[i][j] += a[i].z * b[j].z;
                        acc[i][j] += a[i].w * b[j].w;
                    }
                }
            }
        }
    }

    #pragma unroll
    for (int i = 0; i < 4; ++i) {
        int r = row0 + m0 + i;
        if (r >= N) continue;
        #pragma unroll
        for (int j = 0; j < NREG; ++j) {
            int c = tx + 16 * j;
            float v = acc[i][j] + bias[c];
            if (do_relu) v = fmaxf(v, 0.f);
            out[(size_t)r * BN_T + c] = v;
        }
    }
}

extern "C" void kernel_launch(void* const* d_in, const int* in_sizes, int n_in,
                              void* d_out, int out_size, void* d_ws, size_t ws_size,
                              hipStream_t stream) {
    const float* x   = (const float*)d_in[0];
    const int*   edge = (const int*)d_in[1];   // int32: [2, E]
    const float* Wl0 = (const float*)d_in[2];
    const float* bl0 = (const float*)d_in[3];
    const float* Wr0 = (const float*)d_in[4];
    const float* Wl1 = (const float*)d_in[5];
    const float* bl1 = (const float*)d_in[6];
    const float* Wr1 = (const float*)d_in[7];
    const float* Wl2 = (const float*)d_in[8];
    const float* bl2 = (const float*)d_in[9];
    const float* Wr2 = (const float*)d_in[10];
    float* out = (float*)d_out;

    const int N = in_sizes[0] / D_H;   // 50000
    const int E = in_sizes[1] / 2;     // 800000
    const int* src = edge;
    const int* dst = edge + E;

    char* w = (char*)d_ws;
    float* agg = (float*)w;      w += (size_t)N * D_H * 4;
    float* A   = (float*)w;      w += (size_t)N * D_H * 4;
    float* B   = (float*)w;      w += (size_t)N * D_H * 4;
    int* deg     = (int*)w;      w += (size_t)N * 4;
    int* row_ptr = (int*)w;      w += (size_t)(N + 1) * 4;
    int* cursor  = (int*)w;      w += (size_t)N * 4;
    float* inv_deg = (float*)w;  w += (size_t)N * 4;
    int* bsum    = (int*)w;      w += (size_t)NB_SCAN * 4;
    int* boff    = (int*)w;      w += (size_t)NB_SCAN * 4;
    int* col     = (int*)w;      w += (size_t)E * 4;

    // ---- CSR build ----
    hipMemsetAsync(deg, 0, (size_t)N * 4, stream);
    count_deg_kernel<<<(E + 255) / 256, 256, 0, stream>>>(dst, deg, E);
    scan_reduce_kernel<<<NB_SCAN, 256, 0, stream>>>(deg, bsum, N);
    scan_offsets_kernel<<<1, 256, 0, stream>>>(bsum, boff, row_ptr, N);
    scan_write_kernel<<<NB_SCAN, 256, 0, stream>>>(deg, boff, row_ptr, cursor, inv_deg, N);
    fill_csr_kernel<<<(E + 255) / 256, 256, 0, stream>>>(src, dst, cursor, col, E);

    const int gx = (N + 63) / 64;
    const int agg_grid = (N + 3) / 4;

    // ---- layer 0: x -> A (relu) ----
    aggregate_kernel<<<agg_grid, 256, 0, stream>>>(x, row_ptr, col, inv_deg, agg, N);
    gemm_sage_kernel<128><<<gx, 256, 0, stream>>>(agg, x, Wl0, Wr0, bl0, A, N, 1);

    // ---- layer 1: A -> B (relu) ----
    aggregate_kernel<<<agg_grid, 256, 0, stream>>>(A, row_ptr, col, inv_deg, agg, N);
    gemm_sage_kernel<128><<<gx, 256, 0, stream>>>(agg, A, Wl1, Wr1, bl1, B, N, 1);

    // ---- layer 2: B -> out (no relu) ----
    aggregate_kernel<<<agg_grid, 256, 0, stream>>>(B, row_ptr, col, inv_deg, agg, N);
    gemm_sage_kernel<64><<<gx, 256, 0, stream>>>(agg, B, Wl2, Wr2, bl2, out, N, 0);
}

// Round 4
// 351.669 us; speedup vs baseline: 3.1940x; 3.1940x over previous
//
#include <hip/hip_runtime.h>

// ---------------------------------------------------------------------------
// FlexibleGraphSAGE: 3-layer SAGEConv (mean aggregation).
//   per layer: out = mean_agg(h) @ Wl^T + bl + h @ Wr^T   (+ReLU on layers 0,1)
// R3: internal pipeline in fp16 (inputs/weights rounded once; all accumulation
//     fp32). GEMM = MFMA 16x16x32_f16, LDS-free: A/B frags load straight from
//     row-major X/W (16B/lane contiguous). Aggregate gathers half2 (4B/lane).
//   fp16 (not bf16): 10 mantissa bits -> ~4x less rounding; values O(1).
//   R2 lesson: 4x8 fp32 microtile spilled (VGPR 256, 540MB scratch writes).
//     This kernel: acc 64 VGPR, ~100 total, LDS 0.
// ---------------------------------------------------------------------------

#define D_H 128
#define NB_SCAN 256

typedef _Float16 half8  __attribute__((ext_vector_type(8)));
typedef _Float16 half4v __attribute__((ext_vector_type(4)));
typedef _Float16 half2v __attribute__((ext_vector_type(2)));
typedef float    floatx4 __attribute__((ext_vector_type(4)));

// ---------------- CSR build ----------------
__global__ void count_deg_kernel(const int* __restrict__ dst, int* __restrict__ deg, int E) {
    int e = blockIdx.x * blockDim.x + threadIdx.x;
    if (e < E) atomicAdd(&deg[dst[e]], 1);
}

__global__ __launch_bounds__(256) void scan_reduce_kernel(const int* __restrict__ deg,
                                                          int* __restrict__ bsum, int n) {
    __shared__ int s[256];
    int t = threadIdx.x;
    int i = blockIdx.x * 256 + t;
    int v = (i < n) ? deg[i] : 0;
    s[t] = v;
    __syncthreads();
    for (int off = 128; off > 0; off >>= 1) {
        if (t < off) s[t] += s[t + off];
        __syncthreads();
    }
    if (t == 0) bsum[blockIdx.x] = s[0];
}

__global__ __launch_bounds__(256) void scan_offsets_kernel(const int* __restrict__ bsum,
                                                           int* __restrict__ boff,
                                                           int* __restrict__ row_ptr, int n) {
    __shared__ int s[256];
    int t = threadIdx.x;
    int v = bsum[t];
    s[t] = v;
    __syncthreads();
    for (int off = 1; off < 256; off <<= 1) {
        int tmp = (t >= off) ? s[t - off] : 0;
        __syncthreads();
        s[t] += tmp;
        __syncthreads();
    }
    boff[t] = s[t] - v;
    if (t == 255) row_ptr[n] = s[255];
}

__global__ __launch_bounds__(256) void scan_write_kernel(const int* __restrict__ deg,
                                                         const int* __restrict__ boff,
                                                         int* __restrict__ row_ptr,
                                                         int* __restrict__ cursor,
                                                         float* __restrict__ inv_deg, int n) {
    __shared__ int s[256];
    int t = threadIdx.x;
    int i = blockIdx.x * 256 + t;
    int v = (i < n) ? deg[i] : 0;
    s[t] = v;
    __syncthreads();
    for (int off = 1; off < 256; off <<= 1) {
        int tmp = (t >= off) ? s[t - off] : 0;
        __syncthreads();
        s[t] += tmp;
        __syncthreads();
    }
    if (i < n) {
        int excl = s[t] - v + boff[blockIdx.x];
        row_ptr[i] = excl;
        cursor[i] = excl;
        inv_deg[i] = 1.0f / (float)max(v, 1);
    }
}

__global__ void fill_csr_kernel(const int* __restrict__ src, const int* __restrict__ dst,
                                int* __restrict__ cursor, int* __restrict__ col, int E) {
    int e = blockIdx.x * blockDim.x + threadIdx.x;
    if (e < E) {
        int pos = atomicAdd(&cursor[dst[e]], 1);
        col[pos] = src[e];
    }
}

// ---------------- dtype conversion ----------------
__global__ __launch_bounds__(256) void f2h4_kernel(const float* __restrict__ in,
                                                   _Float16* __restrict__ out, int n4) {
    int i = blockIdx.x * 256 + threadIdx.x;
    if (i < n4) {
        float4 v = ((const float4*)in)[i];
        half4v o = { (_Float16)v.x, (_Float16)v.y, (_Float16)v.z, (_Float16)v.w };
        ((half4v*)out)[i] = o;
    }
}

// all 6 weight matrices in one launch. float4 counts: 4x4096 + 2x2048 = 20480.
__global__ __launch_bounds__(256) void convert_weights_kernel(
        const float* __restrict__ w0, const float* __restrict__ w1,
        const float* __restrict__ w2, const float* __restrict__ w3,
        const float* __restrict__ w4, const float* __restrict__ w5,
        _Float16* __restrict__ o0, _Float16* __restrict__ o1,
        _Float16* __restrict__ o2, _Float16* __restrict__ o3,
        _Float16* __restrict__ o4, _Float16* __restrict__ o5) {
    int i = blockIdx.x * 256 + threadIdx.x;
    const float* in; _Float16* out; int base;
    if      (i <  4096) { in = w0; out = o0; base = 0; }
    else if (i <  8192) { in = w1; out = o1; base = 4096; }
    else if (i < 12288) { in = w2; out = o2; base = 8192; }
    else if (i < 16384) { in = w3; out = o3; base = 12288; }
    else if (i < 18432) { in = w4; out = o4; base = 16384; }
    else                { in = w5; out = o5; base = 18432; }
    int j = i - base;
    float4 v = ((const float4*)in)[j];
    half4v o = { (_Float16)v.x, (_Float16)v.y, (_Float16)v.z, (_Float16)v.w };
    ((half4v*)out)[j] = o;
}

// ---------------- aggregate (mean of neighbor rows, fp16 in/out, fp32 acc) ----
__global__ __launch_bounds__(256) void aggregate_kernel(const _Float16* __restrict__ h,
                                                        const int* __restrict__ row_ptr,
                                                        const int* __restrict__ col,
                                                        const float* __restrict__ inv_deg,
                                                        _Float16* __restrict__ agg, int n) {
    int wave = threadIdx.x >> 6;
    int lane = threadIdx.x & 63;
    int node = blockIdx.x * 4 + wave;
    if (node >= n) return;
    int beg = row_ptr[node];
    int end = row_ptr[node + 1];
    const int off = lane << 1;       // 2 halves per lane
    float ax = 0.f, ay = 0.f;
    for (int base = beg; base < end; base += 64) {
        int m = end - base;
        if (m > 64) m = 64;
        int myc = (lane < m) ? col[base + lane] : 0;
        int j = 0;
        for (; j + 8 <= m; j += 8) {
            int u0 = __shfl(myc, j + 0), u1 = __shfl(myc, j + 1);
            int u2 = __shfl(myc, j + 2), u3 = __shfl(myc, j + 3);
            int u4 = __shfl(myc, j + 4), u5 = __shfl(myc, j + 5);
            int u6 = __shfl(myc, j + 6), u7 = __shfl(myc, j + 7);
            half2v v0 = *(const half2v*)&h[(size_t)u0 * D_H + off];
            half2v v1 = *(const half2v*)&h[(size_t)u1 * D_H + off];
            half2v v2 = *(const half2v*)&h[(size_t)u2 * D_H + off];
            half2v v3 = *(const half2v*)&h[(size_t)u3 * D_H + off];
            half2v v4 = *(const half2v*)&h[(size_t)u4 * D_H + off];
            half2v v5 = *(const half2v*)&h[(size_t)u5 * D_H + off];
            half2v v6 = *(const half2v*)&h[(size_t)u6 * D_H + off];
            half2v v7 = *(const half2v*)&h[(size_t)u7 * D_H + off];
            ax += (float)v0[0] + (float)v1[0] + (float)v2[0] + (float)v3[0]
                + (float)v4[0] + (float)v5[0] + (float)v6[0] + (float)v7[0];
            ay += (float)v0[1] + (float)v1[1] + (float)v2[1] + (float)v3[1]
                + (float)v4[1] + (float)v5[1] + (float)v6[1] + (float)v7[1];
        }
        for (; j < m; ++j) {
            int u = __shfl(myc, j);
            half2v v = *(const half2v*)&h[(size_t)u * D_H + off];
            ax += (float)v[0];
            ay += (float)v[1];
        }
    }
    float s = inv_deg[node];
    half2v o = { (_Float16)(ax * s), (_Float16)(ay * s) };
    *(half2v*)&agg[(size_t)node * D_H + off] = o;
}

// ---------------- MFMA GEMM ----------------
// C[m,c] = sum_k Xa[m,k]*Wa[c,k] + Xh[m,k]*Wh[c,k] + bias[c]
// NT ntiles of 16 cols (8 -> 128-wide, 4 -> 64-wide). 128 threads = 2 waves,
// each wave does 2 strips of 16 rows (32 rows), full width. LDS-free:
// A-frag = X[base+s*16+(lane&15)][k0 + quad*8 ..+7] (16B contiguous/lane)
// B-frag = W[16j+(lane&15)][k0 + quad*8 ..+7]
// C/D: col = lane&15 (+16j), row = base+s*16 + quad*4 + i.
// X arrays are padded to grid*64 rows; OOB rows read garbage, stores guarded.
template<int NT, bool RELU_HALF_OUT>
__global__ __launch_bounds__(128) void gemm_mfma_kernel(
        const _Float16* __restrict__ Xa, const _Float16* __restrict__ Xh,
        const _Float16* __restrict__ Wa, const _Float16* __restrict__ Wh,
        const float* __restrict__ bias,
        _Float16* __restrict__ out_h, float* __restrict__ out_f, int N) {
    const int wave = threadIdx.x >> 6;
    const int lane = threadIdx.x & 63;
    const int r16 = lane & 15;
    const int quad = lane >> 4;
    const int base = blockIdx.x * 64 + wave * 32;
    const int koff = quad * 8;

    floatx4 acc[2][NT];
    #pragma unroll
    for (int s = 0; s < 2; ++s)
        #pragma unroll
        for (int j = 0; j < NT; ++j)
            acc[s][j] = (floatx4){0.f, 0.f, 0.f, 0.f};

    #pragma unroll
    for (int hsel = 0; hsel < 2; ++hsel) {
        const _Float16* __restrict__ X = hsel ? Xh : Xa;
        const _Float16* __restrict__ W = hsel ? Wh : Wa;
        #pragma unroll
        for (int k0 = 0; k0 < 128; k0 += 32) {
            half8 a0 = *(const half8*)&X[(size_t)(base + r16) * 128 + k0 + koff];
            half8 a1 = *(const half8*)&X[(size_t)(base + 16 + r16) * 128 + k0 + koff];
            #pragma unroll
            for (int j = 0; j < NT; ++j) {
                half8 b = *(const half8*)&W[(size_t)(j * 16 + r16) * 128 + k0 + koff];
                acc[0][j] = __builtin_amdgcn_mfma_f32_16x16x32_f16(a0, b, acc[0][j], 0, 0, 0);
                acc[1][j] = __builtin_amdgcn_mfma_f32_16x16x32_f16(a1, b, acc[1][j], 0, 0, 0);
            }
        }
    }

    #pragma unroll
    for (int s = 0; s < 2; ++s) {
        #pragma unroll
        for (int i = 0; i < 4; ++i) {
            int r = base + s * 16 + quad * 4 + i;
            if (r >= N) continue;
            #pragma unroll
            for (int j = 0; j < NT; ++j) {
                int c = j * 16 + r16;
                float v = acc[s][j][i] + bias[c];
                if (RELU_HALF_OUT) {
                    v = fmaxf(v, 0.f);
                    out_h[(size_t)r * (NT * 16) + c] = (_Float16)v;
                } else {
                    out_f[(size_t)r * (NT * 16) + c] = v;
                }
            }
        }
    }
}

extern "C" void kernel_launch(void* const* d_in, const int* in_sizes, int n_in,
                              void* d_out, int out_size, void* d_ws, size_t ws_size,
                              hipStream_t stream) {
    const float* x   = (const float*)d_in[0];
    const int*   edge = (const int*)d_in[1];   // int32: [2, E]
    const float* Wl0 = (const float*)d_in[2];
    const float* bl0 = (const float*)d_in[3];
    const float* Wr0 = (const float*)d_in[4];
    const float* Wl1 = (const float*)d_in[5];
    const float* bl1 = (const float*)d_in[6];
    const float* Wr1 = (const float*)d_in[7];
    const float* Wl2 = (const float*)d_in[8];
    const float* bl2 = (const float*)d_in[9];
    const float* Wr2 = (const float*)d_in[10];
    float* out = (float*)d_out;

    const int N = in_sizes[0] / D_H;   // 50000
    const int E = in_sizes[1] / 2;     // 800000
    const int* src = edge;
    const int* dst = edge + E;

    const int gx = (N + 63) / 64;      // GEMM blocks (64 rows each)
    const int Np = gx * 64;            // padded row count for OOB-safe A loads

    char* w = (char*)d_ws;
    _Float16* xh   = (_Float16*)w;  w += (size_t)Np * D_H * 2;
    _Float16* Ah   = (_Float16*)w;  w += (size_t)Np * D_H * 2;
    _Float16* Bh   = (_Float16*)w;  w += (size_t)Np * D_H * 2;
    _Float16* aggh = (_Float16*)w;  w += (size_t)Np * D_H * 2;
    _Float16* Wl0h = (_Float16*)w;  w += (size_t)128 * 128 * 2;
    _Float16* Wr0h = (_Float16*)w;  w += (size_t)128 * 128 * 2;
    _Float16* Wl1h = (_Float16*)w;  w += (size_t)128 * 128 * 2;
    _Float16* Wr1h = (_Float16*)w;  w += (size_t)128 * 128 * 2;
    _Float16* Wl2h = (_Float16*)w;  w += (size_t)64 * 128 * 2;
    _Float16* Wr2h = (_Float16*)w;  w += (size_t)64 * 128 * 2;
    int* deg     = (int*)w;      w += (size_t)N * 4;
    int* row_ptr = (int*)w;      w += (size_t)(N + 1) * 4;
    int* cursor  = (int*)w;      w += (size_t)N * 4;
    float* inv_deg = (float*)w;  w += (size_t)N * 4;
    int* bsum    = (int*)w;      w += (size_t)NB_SCAN * 4;
    int* boff    = (int*)w;      w += (size_t)NB_SCAN * 4;
    int* col     = (int*)w;      w += (size_t)E * 4;

    // ---- CSR build ----
    hipMemsetAsync(deg, 0, (size_t)N * 4, stream);
    count_deg_kernel<<<(E + 255) / 256, 256, 0, stream>>>(dst, deg, E);
    scan_reduce_kernel<<<NB_SCAN, 256, 0, stream>>>(deg, bsum, N);
    scan_offsets_kernel<<<1, 256, 0, stream>>>(bsum, boff, row_ptr, N);
    scan_write_kernel<<<NB_SCAN, 256, 0, stream>>>(deg, boff, row_ptr, cursor, inv_deg, N);
    fill_csr_kernel<<<(E + 255) / 256, 256, 0, stream>>>(src, dst, cursor, col, E);

    // ---- fp32 -> fp16 conversions ----
    const int n4 = N * D_H / 4;
    f2h4_kernel<<<(n4 + 255) / 256, 256, 0, stream>>>(x, xh, n4);
    convert_weights_kernel<<<80, 256, 0, stream>>>(Wl0, Wr0, Wl1, Wr1, Wl2, Wr2,
                                                   Wl0h, Wr0h, Wl1h, Wr1h, Wl2h, Wr2h);

    const int agg_grid = (N + 3) / 4;

    // ---- layer 0: xh -> Ah (relu) ----
    aggregate_kernel<<<agg_grid, 256, 0, stream>>>(xh, row_ptr, col, inv_deg, aggh, N);
    gemm_mfma_kernel<8, true><<<gx, 128, 0, stream>>>(aggh, xh, Wl0h, Wr0h, bl0, Ah, nullptr, N);

    // ---- layer 1: Ah -> Bh (relu) ----
    aggregate_kernel<<<agg_grid, 256, 0, stream>>>(Ah, row_ptr, col, inv_deg, aggh, N);
    gemm_mfma_kernel<8, true><<<gx, 128, 0, stream>>>(aggh, Ah, Wl1h, Wr1h, bl1, Bh, nullptr, N);

    // ---- layer 2: Bh -> out fp32 (no relu) ----
    aggregate_kernel<<<agg_grid, 256, 0, stream>>>(Bh, row_ptr, col, inv_deg, aggh, N);
    gemm_mfma_kernel<4, false><<<gx, 128, 0, stream>>>(aggh, Bh, Wl2h, Wr2h, bl2, nullptr, out, N);
}